// Round 5
// baseline (1648.361 us; speedup 1.0000x reference)
//
#include <hip/hip_runtime.h>
#include <hip/hip_bf16.h>

typedef __bf16 bf16;
typedef __bf16 bf16x4 __attribute__((ext_vector_type(4)));
typedef __bf16 bf16x8 __attribute__((ext_vector_type(8)));
typedef float floatx4 __attribute__((ext_vector_type(4)));

#define MFMA16(a, b, c) __builtin_amdgcn_mfma_f32_16x16x32_bf16((a), (b), (c), 0, 0, 0)

#define SCALE_F 0.125f            // 1/sqrt(1024/16); reference contracts full d=1024 (single head)

// ---------------------------------------------------------------------------
// fp32 -> bf16 conversion, 4 elems/thread
// ---------------------------------------------------------------------------
__global__ __launch_bounds__(256) void cvt_kernel(const float* __restrict__ in, bf16* __restrict__ out, int n4) {
    int i = blockIdx.x * 256 + threadIdx.x;
    if (i < n4) {
        float4 v = ((const float4*)in)[i];
        bf16x4 o = { (bf16)v.x, (bf16)v.y, (bf16)v.z, (bf16)v.w };
        *(bf16x4*)(out + 4 * (size_t)i) = o;
    }
}

// ---------------------------------------------------------------------------
// Gates (sigmoid-normalized) + selection scores (fp64 accum for deterministic
// top-k ordering). One wave per row. All-fp32 inputs.
// ---------------------------------------------------------------------------
__global__ __launch_bounds__(256) void gates_scores_kernel(const float* __restrict__ x,
                                                           const float* __restrict__ Wg, const float* __restrict__ bg,
                                                           const float* __restrict__ Ws, const float* __restrict__ bs,
                                                           float* __restrict__ gates, float* __restrict__ scores) {
    int row = blockIdx.x * 4 + (threadIdx.x >> 6);
    int lane = threadIdx.x & 63;
    const float* xr = x + (size_t)row * 1024 + lane * 16;
    float g0 = 0.f, g1 = 0.f, g2 = 0.f;
    double sc = 0.0;
#pragma unroll
    for (int i = 0; i < 16; i++) {
        float xv = xr[i];
        int k = lane * 16 + i;
        g0 += xv * Wg[k * 3 + 0];
        g1 += xv * Wg[k * 3 + 1];
        g2 += xv * Wg[k * 3 + 2];
        sc += (double)(xv * Ws[k]);
    }
    for (int off = 1; off < 64; off <<= 1) {
        g0 += __shfl_xor(g0, off);
        g1 += __shfl_xor(g1, off);
        g2 += __shfl_xor(g2, off);
        sc += __shfl_xor(sc, off);
    }
    if (lane == 0) {
        g0 = 1.0f / (1.0f + __expf(-(g0 + bg[0])));
        g1 = 1.0f / (1.0f + __expf(-(g1 + bg[1])));
        g2 = 1.0f / (1.0f + __expf(-(g2 + bg[2])));
        float den = g0 + g1 + g2 + 1e-6f;
        gates[(size_t)row * 3 + 0] = g0 / den;
        gates[(size_t)row * 3 + 1] = g1 / den;
        gates[(size_t)row * 3 + 2] = g2 / den;
        scores[row] = (float)(sc + (double)bs[0]);
    }
}

// ---------------------------------------------------------------------------
// Top-512 of 4096 scores per batch (score desc, idx asc tiebreak), output
// indices ascending. One block of 1024 threads per batch; bitonic sort.
// ---------------------------------------------------------------------------
__global__ __launch_bounds__(1024) void topk_kernel(const float* __restrict__ scores, int* __restrict__ sidx) {
    __shared__ unsigned long long keys[4096];
    int b = blockIdx.x, t = threadIdx.x;
    for (int i = t; i < 4096; i += 1024) {
        float s = scores[b * 4096 + i];
        unsigned u = __float_as_uint(s);
        u = (u & 0x80000000u) ? ~u : (u | 0x80000000u);   // order-preserving map
        keys[i] = ((unsigned long long)(~u) << 32) | (unsigned)i; // asc key => score desc, idx asc
    }
    __syncthreads();
    for (int k = 2; k <= 4096; k <<= 1)
        for (int j = k >> 1; j > 0; j >>= 1) {
            for (int i = t; i < 4096; i += 1024) {
                int p = i ^ j;
                if (p > i) {
                    bool up = ((i & k) == 0);
                    unsigned long long a = keys[i], c = keys[p];
                    if ((a > c) == up) { keys[i] = c; keys[p] = a; }
                }
            }
            __syncthreads();
        }
    unsigned myidx = (t < 512) ? (unsigned)(keys[t] & 0xFFFFFFFFu) : 0u;
    __syncthreads();
    unsigned* ids = (unsigned*)keys;
    if (t < 512) ids[t] = myidx;
    __syncthreads();
    for (int k = 2; k <= 512; k <<= 1)
        for (int j = k >> 1; j > 0; j >>= 1) {
            if (t < 512) {
                int p = t ^ j;
                if (p > t) {
                    bool up = ((t & k) == 0);
                    unsigned a = ids[t], c = ids[p];
                    if ((a > c) == up) { ids[t] = c; ids[p] = a; }
                }
            }
            __syncthreads();
        }
    if (t < 512) sidx[b * 512 + t] = (int)ids[t];
}

// ---------------------------------------------------------------------------
// Gather selected rows of Q/K/V (index masked so a topk bug cannot read OOB)
// ---------------------------------------------------------------------------
__global__ __launch_bounds__(256) void gather_kernel(const bf16* __restrict__ Qf, const bf16* __restrict__ Kf,
                                                     const bf16* __restrict__ Vf, const int* __restrict__ sidx,
                                                     bf16* __restrict__ sq, bf16* __restrict__ sk,
                                                     bf16* __restrict__ sv) {
    int e = blockIdx.x * 256 + threadIdx.x;   // 4*512*128 total
    int col = (e & 127) * 8;
    int i = (e >> 7) & 511;
    int b = e >> 16;
    int src = b * 4096 + (sidx[b * 512 + i] & 4095);
    size_t so = (size_t)src * 1024 + col;
    size_t dofs = (size_t)(b * 512 + i) * 1024 + col;
    *(float4*)(sq + dofs) = *(const float4*)(Qf + so);
    *(float4*)(sk + dofs) = *(const float4*)(Kf + so);
    *(float4*)(sv + dofs) = *(const float4*)(Vf + so);
}

// ---------------------------------------------------------------------------
// GEMM: C(M,N) = A(M,K) @ B + bias (bias fp32).  A,B bf16.
//   BT=true : B supplied as Bt (N x K), ldb = Bt row stride
//   BT=false: B row-major (K x N), ldb = B row stride (in-LDS transpose)
// z-batched: per-block z offsets  off = (z/zdiv)*s?hi + (z%zdiv)*s?lo  (elements)
// F32OUT: fp32 C; ACC: C += (fp32 or bf16 per F32OUT);
// REMAP: A-row r -> C-row (r/mpbA)*mpbC + r%mpbA
// 128x128 tile, 16x16x32 bf16 MFMA, 4 waves, 4x4 frags/wave (m93 pattern).
// ---------------------------------------------------------------------------
template <bool BT, bool F32OUT, bool ACC, bool REMAP>
__global__ __launch_bounds__(256) void gemm2(const bf16* __restrict__ A, const bf16* __restrict__ B,
                                             void* __restrict__ Cv, const float* __restrict__ bias,
                                             int K, int lda, int ldb, int ldc, int zdiv,
                                             size_t sAhi, size_t sAlo, size_t sBhi, size_t sBlo,
                                             size_t sChi, size_t sClo, int mpbA, int mpbC) {
    __shared__ float4 smA[512], smB[512];  // 128x32 bf16 each, 16B-aligned
    bf16* sA = (bf16*)smA;
    bf16* sB = (bf16*)smB;
    const int t = threadIdx.x;
    const int lane = t & 63, quad = lane >> 4, l16 = lane & 15;
    const int wv = t >> 6, wm = wv >> 1, wn = wv & 1;
    const int mt = blockIdx.y, nt = blockIdx.x;
    const int z = blockIdx.z;
    const int zh = z / zdiv, zl = z - zh * zdiv;
    A += (size_t)zh * sAhi + (size_t)zl * sAlo;
    B += (size_t)zh * sBhi + (size_t)zl * sBlo;
    const size_t cofs = (size_t)zh * sChi + (size_t)zl * sClo;

    floatx4 acc[4][4] = {};

    const int sr = t >> 2, scofs = (t & 3) * 8;
    const bf16* Ap = A + (size_t)(mt * 128 + sr) * lda + scofs;
    const size_t rowA64 = (size_t)64 * lda;

    const bf16* Bp;
    int kr = t >> 4, nc = (t & 15) * 8;    // BT=false staging coords
    if constexpr (BT) {
        Bp = B + (size_t)(nt * 128 + sr) * ldb + scofs;
    } else {
        Bp = B + (size_t)kr * ldb + nt * 128 + nc;
    }
    const size_t rowB64 = BT ? (size_t)64 * ldb : (size_t)16 * ldb;

    for (int k0 = 0; k0 < K; k0 += 32) {
        __syncthreads();
        ((float4*)sA)[t]       = *(const float4*)(Ap + k0);
        ((float4*)sA)[t + 256] = *(const float4*)(Ap + rowA64 + k0);
        if constexpr (BT) {
            ((float4*)sB)[t]       = *(const float4*)(Bp + k0);
            ((float4*)sB)[t + 256] = *(const float4*)(Bp + rowB64 + k0);
        } else {
            float4 b0 = *(const float4*)(Bp + (size_t)k0 * ldb);
            float4 b1 = *(const float4*)(Bp + (size_t)k0 * ldb + rowB64);
            bf16 e0[8], e1[8];
            __builtin_memcpy(e0, &b0, 16);
            __builtin_memcpy(e1, &b1, 16);
#pragma unroll
            for (int i = 0; i < 8; i++) {
                sB[(nc + i) * 32 + kr]      = e0[i];
                sB[(nc + i) * 32 + kr + 16] = e1[i];
            }
        }
        __syncthreads();
        bf16x8 af[4], bfr[4];
#pragma unroll
        for (int i = 0; i < 4; i++) af[i] = *(const bf16x8*)(sA + (wm * 64 + i * 16 + l16) * 32 + quad * 8);
#pragma unroll
        for (int j = 0; j < 4; j++) bfr[j] = *(const bf16x8*)(sB + (wn * 64 + j * 16 + l16) * 32 + quad * 8);
#pragma unroll
        for (int i = 0; i < 4; i++)
#pragma unroll
            for (int j = 0; j < 4; j++) acc[i][j] = MFMA16(af[i], bfr[j], acc[i][j]);
    }

#pragma unroll
    for (int i = 0; i < 4; i++) {
        int gr0 = mt * 128 + wm * 64 + i * 16 + quad * 4;
#pragma unroll
        for (int j = 0; j < 4; j++) {
            int gc = nt * 128 + wn * 64 + j * 16 + l16;
            float bvl = bias ? bias[gc] : 0.0f;
#pragma unroll
            for (int r = 0; r < 4; r++) {
                int row = gr0 + r;
                size_t crow = REMAP ? ((size_t)(row / mpbA) * mpbC + (row % mpbA)) : (size_t)row;
                size_t off = cofs + crow * ldc + gc;
                float v = acc[i][j][r] + bvl;
                if constexpr (F32OUT) {
                    float* Cf = (float*)Cv;
                    if constexpr (ACC) v += Cf[off];
                    Cf[off] = v;
                } else {
                    bf16* Cb = (bf16*)Cv;
                    if constexpr (ACC) v += (float)Cb[off];
                    Cb[off] = (bf16)v;
                }
            }
        }
    }
}

// ---------------------------------------------------------------------------
// Row softmax over fp32 scores; writes bf16 P already scaled by the per-row
// gate (gate folds linearly through P@V). One block per row, RL in {256,512,1024}.
// MODE 0: comp rows (B*1024); MODE 1: sel (B*512);
// MODE 2: win — upb windows/batch in this buffer, first window = wbase.
// ---------------------------------------------------------------------------
template <int MODE>
__global__ __launch_bounds__(256) void softmax_kernel(const float* __restrict__ S, bf16* __restrict__ P,
                                                      const float* __restrict__ gates, int RL,
                                                      int upb, int wbase) {
    __shared__ float red[8];
    const int row = blockIdx.x, t = threadIdx.x;
    const float* srow = S + (size_t)row * RL;
    bf16* prow = P + (size_t)row * RL;
    const int npt = RL >> 8;   // 1, 2, or 4 elems/thread
    float v[4];
    float m = -1e30f;
    for (int i = 0; i < npt; i++) { v[i] = srow[t + (i << 8)] * SCALE_F; m = fmaxf(m, v[i]); }
    for (int off = 1; off < 64; off <<= 1) m = fmaxf(m, __shfl_xor(m, off));
    const int wvv = t >> 6, lane = t & 63;
    if (lane == 0) red[wvv] = m;
    __syncthreads();
    m = fmaxf(fmaxf(red[0], red[1]), fmaxf(red[2], red[3]));
    float e[4], s = 0.f;
    for (int i = 0; i < npt; i++) { e[i] = __expf(v[i] - m); s += e[i]; }
    for (int off = 1; off < 64; off <<= 1) s += __shfl_xor(s, off);
    if (lane == 0) red[4 + wvv] = s;
    __syncthreads();
    s = red[4] + red[5] + red[6] + red[7];
    int gpos;
    if (MODE == 0)      { gpos = (row >> 10) * 4096 + (row & 1023); }
    else if (MODE == 1) { gpos = (row >> 9) * 4096 + (row & 511); }
    else                { int zz = row >> 8; gpos = (zz / upb) * 4096 + (wbase + zz % upb) * 256 + (row & 255); }
    const float fac = gates[gpos * 3 + MODE] / s;
    for (int i = 0; i < npt; i++) prow[t + (i << 8)] = (bf16)(e[i] * fac);
}

// ---------------------------------------------------------------------------
// Residual (0.5/0.5) + LayerNorm (no affine), in-place on fp32 out buffer.
// One block per row. x is the original fp32 input.
// ---------------------------------------------------------------------------
__global__ __launch_bounds__(256) void ln_kernel(float* __restrict__ acc, const float* __restrict__ x) {
    __shared__ float red[8];
    int row = blockIdx.x, t = threadIdx.x;
    float4 a = ((const float4*)(acc + (size_t)row * 1024))[t];
    float4 xv = ((const float4*)(x + (size_t)row * 1024))[t];
    float y[4];
    y[0] = 0.5f * a.x + 0.5f * xv.x;
    y[1] = 0.5f * a.y + 0.5f * xv.y;
    y[2] = 0.5f * a.z + 0.5f * xv.z;
    y[3] = 0.5f * a.w + 0.5f * xv.w;
    float s = 0.f, s2 = 0.f;
#pragma unroll
    for (int i = 0; i < 4; i++) { s += y[i]; s2 += y[i] * y[i]; }
    for (int off = 1; off < 64; off <<= 1) { s += __shfl_xor(s, off); s2 += __shfl_xor(s2, off); }
    int wvv = t >> 6, lane = t & 63;
    if (lane == 0) { red[wvv] = s; red[4 + wvv] = s2; }
    __syncthreads();
    s = red[0] + red[1] + red[2] + red[3];
    s2 = red[4] + red[5] + red[6] + red[7];
    float mu = s * (1.0f / 1024.0f);
    float var = s2 * (1.0f / 1024.0f) - mu * mu;
    float rs = rsqrtf(var + 1e-6f);
    float4 o;
    o.x = (y[0] - mu) * rs;
    o.y = (y[1] - mu) * rs;
    o.z = (y[2] - mu) * rs;
    o.w = (y[3] - mu) * rs;
    ((float4*)(acc + (size_t)row * 1024))[t] = o;
}

// ---------------------------------------------------------------------------
extern "C" void kernel_launch(void* const* d_in, const int* in_sizes, int n_in,
                              void* d_out, int out_size, void* d_ws, size_t ws_size,
                              hipStream_t stream) {
    (void)in_sizes; (void)n_in; (void)out_size; (void)ws_size;
    // Reference dtypes are ALL float32 (setup_inputs uses jnp.float32).
    const float* x  = (const float*)d_in[0];
    const float* Wq = (const float*)d_in[1];
    const float* bq = (const float*)d_in[2];
    const float* Wk = (const float*)d_in[3];
    const float* bk = (const float*)d_in[4];
    const float* Wv = (const float*)d_in[5];
    const float* bv = (const float*)d_in[6];
    const float* Wo = (const float*)d_in[7];
    const float* bo = (const float*)d_in[8];
    const float* Wg = (const float*)d_in[9];
    const float* bg = (const float*)d_in[10];
    const float* Wc = (const float*)d_in[11];
    const float* bc = (const float*)d_in[12];
    const float* Ws = (const float*)d_in[13];
    const float* bs = (const float*)d_in[14];
    float* out = (float*)d_out;   // fp32 output, also the projection accumulator

    // ---- workspace layout (~192.3 MB peak; lifetimes annotated) ----
    char* w = (char*)d_ws;
    const size_t MB = 1024 * 1024;
    bf16* qf   = (bf16*)(w + 0 * MB);     // 32 MB; dead after win-S
    bf16* kf   = (bf16*)(w + 32 * MB);    // 32 MB; dead after win-S
    bf16* vf   = (bf16*)(w + 64 * MB);    // 32 MB; dead after win-PV
    bf16* xb   = (bf16*)(w + 96 * MB);    // 32 MB bf16(x); dead after comp + qkv
    bf16* wqb  = (bf16*)(w + 128 * MB);   // 2 MB; dead after cq
    bf16* wkb  = (bf16*)(w + 130 * MB);   // 2
    bf16* wvb  = (bf16*)(w + 132 * MB);   // 2
    bf16* wcb  = (bf16*)(w + 134 * MB);   // 8; dead after comp
    bf16* wob  = (bf16*)(w + 142 * MB);   // 6 (all 3 blocks of Wo); live to the end
    bf16* comp = (bf16*)(w + 148 * MB);   // 8; dead after cq/ck/cv
    bf16* cq   = (bf16*)(w + 156 * MB);   // 8; dead after Scomp
    bf16* ck   = (bf16*)(w + 164 * MB);   // 8; dead after Scomp
    bf16* cv   = (bf16*)(w + 172 * MB);   // 8; dead after comp-PV
    bf16* sq   = (bf16*)(w + 180 * MB);   // 4; sel branch
    bf16* sk   = (bf16*)(w + 184 * MB);   // 4
    bf16* sv   = (bf16*)(w + 188 * MB);   // 4
    float* gatesF  = (float*)(w + 192 * MB);       // 16384*3 fp32
    float* scoresF = gatesF + 16384 * 3;           // 16384 fp32
    int*   sidx    = (int*)(scoresF + 16384);      // 2048 ints (~192.3 MB total)
    // aliased (lifetime-disjoint):
    float* Swin  = (float*)(w + 96 * MB);   // 16 MB over xb (win runs after comp chain)
    bf16* Pwin   = (bf16*)(w + 112 * MB);   // 8 MB
    bf16* win_o  = (bf16*)(w + 0 * MB);     // 32 MB over qf (dead after win-S)
    float* Scomp = (float*)(w + 32 * MB);   // 16 MB over kf (comp S after win-S)
    bf16* Pcomp  = (bf16*)(w + 48 * MB);    // 8 MB
    bf16* comp_o = (bf16*)(w + 56 * MB);    // 8 MB
    float* Ssel  = (float*)(w + 64 * MB);   // 4 MB over vf (sel after win-PV)
    bf16* Psel   = (bf16*)(w + 68 * MB);    // 2 MB
    bf16* sel_o  = (bf16*)(w + 70 * MB);    // 4 MB

    // ---- fp32 -> bf16 conversions ----
    cvt_kernel<<<16384, 256, 0, stream>>>(x, xb, 4194304);          // 16,777,216 elems
    cvt_kernel<<<1024, 256, 0, stream>>>(Wq, wqb, 262144);
    cvt_kernel<<<1024, 256, 0, stream>>>(Wk, wkb, 262144);
    cvt_kernel<<<1024, 256, 0, stream>>>(Wv, wvb, 262144);
    cvt_kernel<<<4096, 256, 0, stream>>>(Wc, wcb, 1048576);
    cvt_kernel<<<3072, 256, 0, stream>>>(Wo, wob, 786432);

    gates_scores_kernel<<<4096, 256, 0, stream>>>(x, Wg, bg, Ws, bs, gatesF, scoresF);
    topk_kernel<<<4, 1024, 0, stream>>>(scoresF, sidx);

    // ---- full-sequence Q/K/V: (16384,1024) = xb @ W (BT=false, weights row-major KxN) ----
    gemm2<false,false,false,false><<<dim3(8,128,1), 256, 0, stream>>>(xb, wqb, qf, bq, 1024, 1024,1024,1024, 1, 0,0,0,0,0,0, 1,1);
    gemm2<false,false,false,false><<<dim3(8,128,1), 256, 0, stream>>>(xb, wkb, kf, bk, 1024, 1024,1024,1024, 1, 0,0,0,0,0,0, 1,1);
    gemm2<false,false,false,false><<<dim3(8,128,1), 256, 0, stream>>>(xb, wvb, vf, bv, 1024, 1024,1024,1024, 1, 0,0,0,0,0,0, 1,1);

    // ---- compressed tokens: xb viewed (4096,4096) @ Wc, then comp QKV (frees xb) ----
    gemm2<false,false,false,false><<<dim3(8,32,1), 256, 0, stream>>>(xb, wcb, comp, bc, 4096, 4096,1024,1024, 1, 0,0,0,0,0,0, 1,1);
    gemm2<false,false,false,false><<<dim3(8,32,1), 256, 0, stream>>>(comp, wqb, cq, bq, 1024, 1024,1024,1024, 1, 0,0,0,0,0,0, 1,1);
    gemm2<false,false,false,false><<<dim3(8,32,1), 256, 0, stream>>>(comp, wkb, ck, bk, 1024, 1024,1024,1024, 1, 0,0,0,0,0,0, 1,1);
    gemm2<false,false,false,false><<<dim3(8,32,1), 256, 0, stream>>>(comp, wvb, cv, bv, 1024, 1024,1024,1024, 1, 0,0,0,0,0,0, 1,1);

    gather_kernel<<<1024, 256, 0, stream>>>(qf, kf, vf, sidx, sq, sk, sv);

    // ---- WIN branch: 64 z-units = 4 batches x 16 windows.
    //      window w: queries/keys = qf/kf rows (b*4096 + w*128 .. +255), output rows b*4096 + w*256 .. ----
    gemm2<true,true,false,false><<<dim3(2,2,64), 256, 0, stream>>>(
        qf, kf, Swin, nullptr, 1024, 1024,1024,256, 16,
        (size_t)4194304,(size_t)131072, (size_t)4194304,(size_t)131072, (size_t)1048576,(size_t)65536, 1,1);
    softmax_kernel<2><<<16384, 256, 0, stream>>>(Swin, Pwin, gatesF, 256, 16, 0);
    gemm2<false,false,false,false><<<dim3(8,2,64), 256, 0, stream>>>(
        Pwin, vf, win_o, nullptr, 256, 256,1024,1024, 16,
        (size_t)1048576,(size_t)65536, (size_t)4194304,(size_t)131072, (size_t)4194304,(size_t)262144, 1,1);
    // win projection: writes every out element fp32 (clears poison), adds bias
    gemm2<false,true,false,false><<<dim3(8,128,1), 256, 0, stream>>>(
        win_o, wob + (size_t)2048 * 1024, out, bo, 1024, 1024,1024,1024, 1, 0,0,0,0,0,0, 1,1);

    // ---- COMP branch ----
    gemm2<true,true,false,false><<<dim3(8,8,4), 256, 0, stream>>>(cq, ck, Scomp, nullptr, 1024, 1024,1024,1024, 1,
        (size_t)1048576,0, (size_t)1048576,0, (size_t)1048576,0, 1,1);
    softmax_kernel<0><<<4096, 256, 0, stream>>>(Scomp, Pcomp, gatesF, 1024, 0, 0);
    gemm2<false,false,false,false><<<dim3(8,8,4), 256, 0, stream>>>(Pcomp, cv, comp_o, nullptr, 1024, 1024,1024,1024, 1,
        (size_t)1048576,0, (size_t)1048576,0, (size_t)1048576,0, 1,1);
    gemm2<false,true,true,true><<<dim3(8,32,1), 256, 0, stream>>>(
        comp_o, wob, out, nullptr, 1024, 1024,1024,1024, 1, 0,0,0,0,0,0, 1024,4096);

    // ---- SEL branch ----
    gemm2<true,true,false,false><<<dim3(4,4,4), 256, 0, stream>>>(sq, sk, Ssel, nullptr, 1024, 1024,1024,512, 1,
        (size_t)524288,0, (size_t)524288,0, (size_t)262144,0, 1,1);
    softmax_kernel<1><<<2048, 256, 0, stream>>>(Ssel, Psel, gatesF, 512, 0, 0);
    gemm2<false,false,false,false><<<dim3(8,4,4), 256, 0, stream>>>(Psel, sv, sel_o, nullptr, 512, 512,1024,1024, 1,
        (size_t)262144,0, (size_t)524288,0, (size_t)524288,0, 1,1);
    gemm2<false,true,true,true><<<dim3(8,16,1), 256, 0, stream>>>(
        sel_o, wob + (size_t)1024 * 1024, out, nullptr, 1024, 1024,1024,1024, 1, 0,0,0,0,0,0, 512,4096);

    // ---- residual + LN, in place on fp32 d_out ----
    ln_kernel<<<16384, 256, 0, stream>>>(out, x);
}

// Round 6
// 1135.564 us; speedup vs baseline: 1.4516x; 1.4516x over previous
//
#include <hip/hip_runtime.h>
#include <hip/hip_bf16.h>

typedef __bf16 bf16;
typedef __bf16 bf16x4 __attribute__((ext_vector_type(4)));
typedef __bf16 bf16x8 __attribute__((ext_vector_type(8)));
typedef float floatx4 __attribute__((ext_vector_type(4)));

#define MFMA16(a, b, c) __builtin_amdgcn_mfma_f32_16x16x32_bf16((a), (b), (c), 0, 0, 0)
#define SCALE_F 0.125f

// async global->LDS, 16B per lane; LDS dest = wave-uniform base + lane*16
#define GLDS(gp, lp) __builtin_amdgcn_global_load_lds( \
    (const __attribute__((address_space(1))) void*)(gp), \
    (__attribute__((address_space(3))) void*)(lp), 16, 0, 0)

// ---------------------------------------------------------------------------
// out[row] = bias (fp32 broadcast) — base for the 3 accumulating projections
// ---------------------------------------------------------------------------
__global__ __launch_bounds__(256) void binit_kernel(float* __restrict__ out, const float* __restrict__ bo) {
    int row = blockIdx.x, t = threadIdx.x;
    float4 b = ((const float4*)bo)[t];
    ((float4*)(out + (size_t)row * 1024))[t] = b;
}

// ---------------------------------------------------------------------------
// fp32 -> bf16 conversion, 4 elems/thread
// ---------------------------------------------------------------------------
__global__ __launch_bounds__(256) void cvt_kernel(const float* __restrict__ in, bf16* __restrict__ out, int n4) {
    int i = blockIdx.x * 256 + threadIdx.x;
    if (i < n4) {
        float4 v = ((const float4*)in)[i];
        bf16x4 o = { (bf16)v.x, (bf16)v.y, (bf16)v.z, (bf16)v.w };
        *(bf16x4*)(out + 4 * (size_t)i) = o;
    }
}

// ---------------------------------------------------------------------------
// fused transpose + fp32->bf16: in (R x C) fp32 -> out (C x R) bf16
// ---------------------------------------------------------------------------
__global__ __launch_bounds__(256) void tcvt_kernel(const float* __restrict__ in, bf16* __restrict__ out,
                                                   int R, int C) {
    __shared__ float tile[32][33];
    int bx = blockIdx.x * 32, by = blockIdx.y * 32;
    int tx = threadIdx.x, ty = threadIdx.y;   // block (32,8)
#pragma unroll
    for (int i = 0; i < 32; i += 8)
        tile[ty + i][tx] = in[(size_t)(by + ty + i) * C + bx + tx];
    __syncthreads();
#pragma unroll
    for (int i = 0; i < 32; i += 8)
        out[(size_t)(bx + ty + i) * R + by + tx] = (bf16)tile[tx][ty + i];
}

// ---------------------------------------------------------------------------
// bf16 transpose: in (R x C) -> out (C x R)
// ---------------------------------------------------------------------------
__global__ __launch_bounds__(256) void tbf_kernel(const bf16* __restrict__ in, bf16* __restrict__ out,
                                                  int R, int C) {
    __shared__ bf16 tile[32][33];
    int bx = blockIdx.x * 32, by = blockIdx.y * 32;
    int tx = threadIdx.x, ty = threadIdx.y;   // block (32,8)
#pragma unroll
    for (int i = 0; i < 32; i += 8)
        tile[ty + i][tx] = in[(size_t)(by + ty + i) * C + bx + tx];
    __syncthreads();
#pragma unroll
    for (int i = 0; i < 32; i += 8)
        out[(size_t)(bx + ty + i) * R + by + tx] = tile[tx][ty + i];
}

// ---------------------------------------------------------------------------
// Gates (sigmoid-normalized) + selection scores (fp64 accum for deterministic
// top-k ordering). One wave per row. fp32 inputs.
// ---------------------------------------------------------------------------
__global__ __launch_bounds__(256) void gates_scores_kernel(const float* __restrict__ x,
                                                           const float* __restrict__ Wg, const float* __restrict__ bg,
                                                           const float* __restrict__ Ws, const float* __restrict__ bs,
                                                           float* __restrict__ gates, float* __restrict__ scores) {
    int row = blockIdx.x * 4 + (threadIdx.x >> 6);
    int lane = threadIdx.x & 63;
    const float* xr = x + (size_t)row * 1024 + lane * 16;
    float g0 = 0.f, g1 = 0.f, g2 = 0.f;
    double sc = 0.0;
#pragma unroll
    for (int i = 0; i < 16; i++) {
        float xv = xr[i];
        int k = lane * 16 + i;
        g0 += xv * Wg[k * 3 + 0];
        g1 += xv * Wg[k * 3 + 1];
        g2 += xv * Wg[k * 3 + 2];
        sc += (double)(xv * Ws[k]);
    }
    for (int off = 1; off < 64; off <<= 1) {
        g0 += __shfl_xor(g0, off);
        g1 += __shfl_xor(g1, off);
        g2 += __shfl_xor(g2, off);
        sc += __shfl_xor(sc, off);
    }
    if (lane == 0) {
        g0 = 1.0f / (1.0f + __expf(-(g0 + bg[0])));
        g1 = 1.0f / (1.0f + __expf(-(g1 + bg[1])));
        g2 = 1.0f / (1.0f + __expf(-(g2 + bg[2])));
        float den = g0 + g1 + g2 + 1e-6f;
        gates[(size_t)row * 3 + 0] = g0 / den;
        gates[(size_t)row * 3 + 1] = g1 / den;
        gates[(size_t)row * 3 + 2] = g2 / den;
        scores[row] = (float)(sc + (double)bs[0]);
    }
}

// ---------------------------------------------------------------------------
// Top-512 of 4096 per batch (score desc, idx asc tiebreak), output ascending.
// ---------------------------------------------------------------------------
__global__ __launch_bounds__(1024) void topk_kernel(const float* __restrict__ scores, int* __restrict__ sidx) {
    __shared__ unsigned long long keys[4096];
    int b = blockIdx.x, t = threadIdx.x;
    for (int i = t; i < 4096; i += 1024) {
        float s = scores[b * 4096 + i];
        unsigned u = __float_as_uint(s);
        u = (u & 0x80000000u) ? ~u : (u | 0x80000000u);
        keys[i] = ((unsigned long long)(~u) << 32) | (unsigned)i;
    }
    __syncthreads();
    for (int k = 2; k <= 4096; k <<= 1)
        for (int j = k >> 1; j > 0; j >>= 1) {
            for (int i = t; i < 4096; i += 1024) {
                int p = i ^ j;
                if (p > i) {
                    bool up = ((i & k) == 0);
                    unsigned long long a = keys[i], c = keys[p];
                    if ((a > c) == up) { keys[i] = c; keys[p] = a; }
                }
            }
            __syncthreads();
        }
    unsigned myidx = (t < 512) ? (unsigned)(keys[t] & 0xFFFFFFFFu) : 0u;
    __syncthreads();
    unsigned* ids = (unsigned*)keys;
    if (t < 512) ids[t] = myidx;
    __syncthreads();
    for (int k = 2; k <= 512; k <<= 1)
        for (int j = k >> 1; j > 0; j >>= 1) {
            if (t < 512) {
                int p = t ^ j;
                if (p > t) {
                    bool up = ((t & k) == 0);
                    unsigned a = ids[t], c = ids[p];
                    if ((a > c) == up) { ids[t] = c; ids[p] = a; }
                }
            }
            __syncthreads();
        }
    if (t < 512) sidx[b * 512 + t] = (int)ids[t];
}

// ---------------------------------------------------------------------------
// Gather selected rows of Q/K/V
// ---------------------------------------------------------------------------
__global__ __launch_bounds__(256) void gather_kernel(const bf16* __restrict__ Qf, const bf16* __restrict__ Kf,
                                                     const bf16* __restrict__ Vf, const int* __restrict__ sidx,
                                                     bf16* __restrict__ sq, bf16* __restrict__ sk,
                                                     bf16* __restrict__ sv) {
    int e = blockIdx.x * 256 + threadIdx.x;
    int col = (e & 127) * 8;
    int i = (e >> 7) & 511;
    int b = e >> 16;
    int src = b * 4096 + (sidx[b * 512 + i] & 4095);
    size_t so = (size_t)src * 1024 + col;
    size_t dofs = (size_t)(b * 512 + i) * 1024 + col;
    *(float4*)(sq + dofs) = *(const float4*)(Qf + so);
    *(float4*)(sk + dofs) = *(const float4*)(Kf + so);
    *(float4*)(sv + dofs) = *(const float4*)(Vf + so);
}

// ---------------------------------------------------------------------------
// GEMM (BT only): C(M,N) = A(M,K) @ Bt(N,K)^T + bias. m97 pattern:
// 128x128 tile, 16x16x32 bf16 MFMA, 4 waves, 4x4 frags, global_load_lds(16).
// z-batched: off = (z/zdiv)*s?hi + (z%zdiv)*s?lo (elements).
// F32OUT: fp32 C; ACC: C+=; REMAP: A-row r -> C-row (r/mpbA)*mpbC + r%mpbA.
// ---------------------------------------------------------------------------
template <bool F32OUT, bool ACC, bool REMAP>
__global__ __launch_bounds__(256) void gemm3(const bf16* __restrict__ A, const bf16* __restrict__ Bt,
                                             void* __restrict__ Cv, const float* __restrict__ bias,
                                             int K, int lda, int ldb, int ldc, int zdiv,
                                             size_t sAhi, size_t sAlo, size_t sBhi, size_t sBlo,
                                             size_t sChi, size_t sClo, int mpbA, int mpbC) {
    __shared__ float4 smA[512], smB[512];  // 128x32 bf16 each
    bf16* sA = (bf16*)smA;
    bf16* sB = (bf16*)smB;
    const int t = threadIdx.x;
    const int lane = t & 63, quad = lane >> 4, l16 = lane & 15;
    const int wv = t >> 6, wm = wv >> 1, wn = wv & 1;
    const int mt = blockIdx.y, nt = blockIdx.x;
    const int z = blockIdx.z;
    const int zh = z / zdiv, zl = z - zh * zdiv;
    A  += (size_t)zh * sAhi + (size_t)zl * sAlo;
    Bt += (size_t)zh * sBhi + (size_t)zl * sBlo;
    const size_t cofs = (size_t)zh * sChi + (size_t)zl * sClo;

    floatx4 acc[4][4] = {};

    // staging: thread t covers LDS bytes [t*16, t*16+16) (rows 0..63) and
    // [4096 + t*16, ...) (rows 64..127) — contiguous in lane order per wave.
    const bf16* Ap = A + (size_t)(mt * 128 + (t >> 2)) * lda + (t & 3) * 8;
    const bf16* Bp = Bt + (size_t)(nt * 128 + (t >> 2)) * ldb + (t & 3) * 8;
    const size_t rA = (size_t)64 * lda, rB = (size_t)64 * ldb;
    bf16* lA0 = sA + wv * 512;          // wave-uniform LDS bases
    bf16* lA1 = sA + 2048 + wv * 512;
    bf16* lB0 = sB + wv * 512;
    bf16* lB1 = sB + 2048 + wv * 512;

    for (int k0 = 0; k0 < K; k0 += 32) {
        __syncthreads();
        GLDS(Ap + k0,      lA0);
        GLDS(Ap + rA + k0, lA1);
        GLDS(Bp + k0,      lB0);
        GLDS(Bp + rB + k0, lB1);
        __syncthreads();   // compiler emits s_waitcnt vmcnt(0) before s_barrier
        bf16x8 af[4], bfr[4];
#pragma unroll
        for (int i = 0; i < 4; i++) af[i] = *(const bf16x8*)(sA + (wm * 64 + i * 16 + l16) * 32 + quad * 8);
#pragma unroll
        for (int j = 0; j < 4; j++) bfr[j] = *(const bf16x8*)(sB + (wn * 64 + j * 16 + l16) * 32 + quad * 8);
#pragma unroll
        for (int i = 0; i < 4; i++)
#pragma unroll
            for (int j = 0; j < 4; j++) acc[i][j] = MFMA16(af[i], bfr[j], acc[i][j]);
    }

#pragma unroll
    for (int i = 0; i < 4; i++) {
        int gr0 = mt * 128 + wm * 64 + i * 16 + quad * 4;
#pragma unroll
        for (int j = 0; j < 4; j++) {
            int gc = nt * 128 + wn * 64 + j * 16 + l16;
            float bvl = bias ? bias[gc] : 0.0f;
#pragma unroll
            for (int r = 0; r < 4; r++) {
                int row = gr0 + r;
                size_t crow = REMAP ? ((size_t)(row / mpbA) * mpbC + (row % mpbA)) : (size_t)row;
                size_t off = cofs + crow * ldc + gc;
                float v = acc[i][j][r] + bvl;
                if constexpr (F32OUT) {
                    float* Cf = (float*)Cv;
                    if constexpr (ACC) v += Cf[off];
                    Cf[off] = v;
                } else {
                    bf16* Cb = (bf16*)Cv;
                    if constexpr (ACC) v += (float)Cb[off];
                    Cb[off] = (bf16)v;
                }
            }
        }
    }
}

// ---------------------------------------------------------------------------
// Row softmax (fp32 scores -> bf16 P, gate folded in). One block per row.
// MODE 0: comp (B*1024); MODE 1: sel (B*512); MODE 2: win (upb windows/batch).
// ---------------------------------------------------------------------------
template <int MODE>
__global__ __launch_bounds__(256) void softmax_kernel(const float* __restrict__ S, bf16* __restrict__ P,
                                                      const float* __restrict__ gates, int RL,
                                                      int upb, int wbase) {
    __shared__ float red[8];
    const int row = blockIdx.x, t = threadIdx.x;
    const float* srow = S + (size_t)row * RL;
    bf16* prow = P + (size_t)row * RL;
    const int npt = RL >> 8;
    float v[4];
    float m = -1e30f;
    for (int i = 0; i < npt; i++) { v[i] = srow[t + (i << 8)] * SCALE_F; m = fmaxf(m, v[i]); }
    for (int off = 1; off < 64; off <<= 1) m = fmaxf(m, __shfl_xor(m, off));
    const int wvv = t >> 6, lane = t & 63;
    if (lane == 0) red[wvv] = m;
    __syncthreads();
    m = fmaxf(fmaxf(red[0], red[1]), fmaxf(red[2], red[3]));
    float e[4], s = 0.f;
    for (int i = 0; i < npt; i++) { e[i] = __expf(v[i] - m); s += e[i]; }
    for (int off = 1; off < 64; off <<= 1) s += __shfl_xor(s, off);
    if (lane == 0) red[4 + wvv] = s;
    __syncthreads();
    s = red[4] + red[5] + red[6] + red[7];
    int gpos;
    if (MODE == 0)      { gpos = (row >> 10) * 4096 + (row & 1023); }
    else if (MODE == 1) { gpos = (row >> 9) * 4096 + (row & 511); }
    else                { int zz = row >> 8; gpos = (zz / upb) * 4096 + (wbase + zz % upb) * 256 + (row & 255); }
    const float fac = gates[gpos * 3 + MODE] / s;
    for (int i = 0; i < npt; i++) prow[t + (i << 8)] = (bf16)(e[i] * fac);
}

// ---------------------------------------------------------------------------
// Residual (0.5/0.5) + LayerNorm, in-place on fp32 out. One block per row.
// ---------------------------------------------------------------------------
__global__ __launch_bounds__(256) void ln_kernel(float* __restrict__ acc, const float* __restrict__ x) {
    __shared__ float red[8];
    int row = blockIdx.x, t = threadIdx.x;
    float4 a = ((const float4*)(acc + (size_t)row * 1024))[t];
    float4 xv = ((const float4*)(x + (size_t)row * 1024))[t];
    float y[4];
    y[0] = 0.5f * a.x + 0.5f * xv.x;
    y[1] = 0.5f * a.y + 0.5f * xv.y;
    y[2] = 0.5f * a.z + 0.5f * xv.z;
    y[3] = 0.5f * a.w + 0.5f * xv.w;
    float s = 0.f, s2 = 0.f;
#pragma unroll
    for (int i = 0; i < 4; i++) { s += y[i]; s2 += y[i] * y[i]; }
    for (int off = 1; off < 64; off <<= 1) { s += __shfl_xor(s, off); s2 += __shfl_xor(s2, off); }
    int wvv = t >> 6, lane = t & 63;
    if (lane == 0) { red[wvv] = s; red[4 + wvv] = s2; }
    __syncthreads();
    s = red[0] + red[1] + red[2] + red[3];
    s2 = red[4] + red[5] + red[6] + red[7];
    float mu = s * (1.0f / 1024.0f);
    float var = s2 * (1.0f / 1024.0f) - mu * mu;
    float rs = rsqrtf(var + 1e-6f);
    float4 o;
    o.x = (y[0] - mu) * rs;
    o.y = (y[1] - mu) * rs;
    o.z = (y[2] - mu) * rs;
    o.w = (y[3] - mu) * rs;
    ((float4*)(acc + (size_t)row * 1024))[t] = o;
}

// ---------------------------------------------------------------------------
extern "C" void kernel_launch(void* const* d_in, const int* in_sizes, int n_in,
                              void* d_out, int out_size, void* d_ws, size_t ws_size,
                              hipStream_t stream) {
    (void)in_sizes; (void)n_in; (void)out_size; (void)ws_size;
    const float* x  = (const float*)d_in[0];
    const float* Wq = (const float*)d_in[1];
    const float* bq = (const float*)d_in[2];
    const float* Wk = (const float*)d_in[3];
    const float* bk = (const float*)d_in[4];
    const float* Wv = (const float*)d_in[5];
    const float* bv = (const float*)d_in[6];
    const float* Wo = (const float*)d_in[7];
    const float* bo = (const float*)d_in[8];
    const float* Wg = (const float*)d_in[9];
    const float* bg = (const float*)d_in[10];
    const float* Wc = (const float*)d_in[11];
    const float* bc = (const float*)d_in[12];
    const float* Ws = (const float*)d_in[13];
    const float* bs = (const float*)d_in[14];
    float* out = (float*)d_out;

    // ---- workspace (~172.3 MB peak; regions reused across phases) ----
    char* w = (char*)d_ws;
    const size_t MB = 1024 * 1024;
    // region A (0-32): xb -> sel bufs -> comp bufs -> Pwin
    bf16* xb    = (bf16*)(w + 0 * MB);
    bf16* sq    = (bf16*)(w + 0 * MB);
    bf16* sk    = (bf16*)(w + 4 * MB);
    bf16* sv    = (bf16*)(w + 8 * MB);
    bf16* svT   = (bf16*)(w + 12 * MB);
    float* Ssel = (float*)(w + 16 * MB);
    bf16* Psel  = (bf16*)(w + 20 * MB);
    bf16* sel_o = (bf16*)(w + 22 * MB);
    bf16* cq    = (bf16*)(w + 0 * MB);
    bf16* ck    = (bf16*)(w + 8 * MB);
    bf16* cv    = (bf16*)(w + 16 * MB);
    bf16* Pcomp = (bf16*)(w + 24 * MB);
    bf16* Pwin  = (bf16*)(w + 0 * MB);
    // persistent mid regions
    bf16* qf    = (bf16*)(w + 32 * MB);    // live QKV -> S_win; then vfT
    bf16* kf    = (bf16*)(w + 64 * MB);    // live QKV -> S_win; then win_o
    bf16* vf    = (bf16*)(w + 96 * MB);    // live QKV -> tbf vfT
    bf16* vfT   = (bf16*)(w + 32 * MB);
    bf16* win_o = (bf16*)(w + 64 * MB);
    bf16* comp  = (bf16*)(w + 128 * MB);   // live comp-GEMM -> comp-qkv
    // region B (136-152): Scomp -> (cvT, comp_o) -> Swin
    float* Scomp  = (float*)(w + 136 * MB);
    bf16* cvT     = (bf16*)(w + 136 * MB);
    bf16* comp_o  = (bf16*)(w + 144 * MB);
    float* Swin   = (float*)(w + 136 * MB);
    // weights (transposed bf16) + small
    bf16* woT0 = (bf16*)(w + 152 * MB);
    bf16* woT1 = (bf16*)(w + 154 * MB);
    bf16* woT2 = (bf16*)(w + 156 * MB);
    bf16* wcT  = (bf16*)(w + 158 * MB);
    bf16* wqT  = (bf16*)(w + 166 * MB);
    bf16* wkT  = (bf16*)(w + 168 * MB);
    bf16* wvT  = (bf16*)(w + 170 * MB);
    float* gatesF  = (float*)(w + 172 * MB);
    float* scoresF = gatesF + 16384 * 3;
    int*   sidx    = (int*)(scoresF + 16384);

    dim3 tb(32, 8);

    binit_kernel<<<16384, 256, 0, stream>>>(out, bo);
    cvt_kernel<<<16384, 256, 0, stream>>>(x, xb, 4194304);
    tcvt_kernel<<<dim3(32, 32), tb, 0, stream>>>(Wq, wqT, 1024, 1024);
    tcvt_kernel<<<dim3(32, 32), tb, 0, stream>>>(Wk, wkT, 1024, 1024);
    tcvt_kernel<<<dim3(32, 32), tb, 0, stream>>>(Wv, wvT, 1024, 1024);
    tcvt_kernel<<<dim3(32, 128), tb, 0, stream>>>(Wc, wcT, 4096, 1024);
    tcvt_kernel<<<dim3(32, 32), tb, 0, stream>>>(Wo, woT0, 1024, 1024);
    tcvt_kernel<<<dim3(32, 32), tb, 0, stream>>>(Wo + (size_t)1048576, woT1, 1024, 1024);
    tcvt_kernel<<<dim3(32, 32), tb, 0, stream>>>(Wo + (size_t)2097152, woT2, 1024, 1024);

    gates_scores_kernel<<<4096, 256, 0, stream>>>(x, Wg, bg, Ws, bs, gatesF, scoresF);
    topk_kernel<<<4, 1024, 0, stream>>>(scoresF, sidx);

    // ---- full-sequence Q/K/V ----
    gemm3<false,false,false><<<dim3(8,128,1), 256, 0, stream>>>(xb, wqT, qf, bq, 1024, 1024,1024,1024, 1, 0,0,0,0,0,0, 1,1);
    gemm3<false,false,false><<<dim3(8,128,1), 256, 0, stream>>>(xb, wkT, kf, bk, 1024, 1024,1024,1024, 1, 0,0,0,0,0,0, 1,1);
    gemm3<false,false,false><<<dim3(8,128,1), 256, 0, stream>>>(xb, wvT, vf, bv, 1024, 1024,1024,1024, 1, 0,0,0,0,0,0, 1,1);
    // ---- compressed tokens: xb viewed (4096,4096) @ wcT^T (last xb reader) ----
    gemm3<false,false,false><<<dim3(8,32,1), 256, 0, stream>>>(xb, wcT, comp, bc, 4096, 4096,4096,1024, 1, 0,0,0,0,0,0, 1,1);

    // ---- SEL branch (region A after xb dead) ----
    gather_kernel<<<1024, 256, 0, stream>>>(qf, kf, vf, sidx, sq, sk, sv);
    gemm3<true,false,false><<<dim3(4,4,4), 256, 0, stream>>>(sq, sk, Ssel, nullptr, 1024, 1024,1024,512, 1,
        (size_t)524288,0, (size_t)524288,0, (size_t)262144,0, 1,1);
    softmax_kernel<1><<<2048, 256, 0, stream>>>(Ssel, Psel, gatesF, 512, 0, 0);
    tbf_kernel<<<dim3(32, 64), tb, 0, stream>>>(sv, svT, 2048, 1024);
    gemm3<false,false,false><<<dim3(8,4,4), 256, 0, stream>>>(Psel, svT, sel_o, nullptr, 512, 512,2048,1024, 1,
        (size_t)262144,0, (size_t)512,0, (size_t)524288,0, 1,1);
    gemm3<true,true,true><<<dim3(8,16,1), 256, 0, stream>>>(sel_o, woT1, out, nullptr, 1024, 1024,1024,1024, 1,
        0,0,0,0,0,0, 512,4096);

    // ---- COMP branch ----
    gemm3<false,false,false><<<dim3(8,32,1), 256, 0, stream>>>(comp, wqT, cq, bq, 1024, 1024,1024,1024, 1, 0,0,0,0,0,0, 1,1);
    gemm3<false,false,false><<<dim3(8,32,1), 256, 0, stream>>>(comp, wkT, ck, bk, 1024, 1024,1024,1024, 1, 0,0,0,0,0,0, 1,1);
    gemm3<false,false,false><<<dim3(8,32,1), 256, 0, stream>>>(comp, wvT, cv, bv, 1024, 1024,1024,1024, 1, 0,0,0,0,0,0, 1,1);
    gemm3<true,false,false><<<dim3(8,8,4), 256, 0, stream>>>(cq, ck, Scomp, nullptr, 1024, 1024,1024,1024, 1,
        (size_t)1048576,0, (size_t)1048576,0, (size_t)1048576,0, 1,1);
    softmax_kernel<0><<<4096, 256, 0, stream>>>(Scomp, Pcomp, gatesF, 1024, 0, 0);
    tbf_kernel<<<dim3(32, 128), tb, 0, stream>>>(cv, cvT, 4096, 1024);   // Scomp dead
    gemm3<false,false,false><<<dim3(8,8,4), 256, 0, stream>>>(Pcomp, cvT, comp_o, nullptr, 1024, 1024,4096,1024, 1,
        (size_t)1048576,0, (size_t)1024,0, (size_t)1048576,0, 1,1);
    gemm3<true,true,true><<<dim3(8,32,1), 256, 0, stream>>>(comp_o, woT0, out, nullptr, 1024, 1024,1024,1024, 1,
        0,0,0,0,0,0, 1024,4096);

    // ---- WIN branch: 64 z = 4 batches x 16 windows ----
    gemm3<true,false,false><<<dim3(2,2,64), 256, 0, stream>>>(qf, kf, Swin, nullptr, 1024, 1024,1024,256, 16,
        (size_t)4194304,(size_t)131072, (size_t)4194304,(size_t)131072, (size_t)1048576,(size_t)65536, 1,1);
    softmax_kernel<2><<<16384, 256, 0, stream>>>(Swin, Pwin, gatesF, 256, 16, 0);
    tbf_kernel<<<dim3(32, 512), tb, 0, stream>>>(vf, vfT, 16384, 1024);  // qf dead after S_win
    gemm3<false,false,false><<<dim3(8,2,64), 256, 0, stream>>>(Pwin, vfT, win_o, nullptr, 256, 256,16384,1024, 16,
        (size_t)1048576,(size_t)65536, (size_t)4096,(size_t)128, (size_t)4194304,(size_t)262144, 1,1);
    gemm3<true,true,false><<<dim3(8,128,1), 256, 0, stream>>>(win_o, woT2, out, nullptr, 1024, 1024,1024,1024, 1,
        0,0,0,0,0,0, 1,1);

    // ---- residual + LN in place on fp32 d_out ----
    ln_kernel<<<16384, 256, 0, stream>>>(out, x);
}

// Round 7
// 983.868 us; speedup vs baseline: 1.6754x; 1.1542x over previous
//
#include <hip/hip_runtime.h>
#include <hip/hip_bf16.h>

typedef __bf16 bf16;
typedef __bf16 bf16x4 __attribute__((ext_vector_type(4)));
typedef __bf16 bf16x8 __attribute__((ext_vector_type(8)));
typedef float floatx4 __attribute__((ext_vector_type(4)));

#define MFMA16(a, b, c) __builtin_amdgcn_mfma_f32_16x16x32_bf16((a), (b), (c), 0, 0, 0)
#define SCALE_F 0.125f

// async global->LDS, 16B per lane; LDS dest = wave-uniform base + lane*16
#define GLDS(gp, lp) __builtin_amdgcn_global_load_lds( \
    (const __attribute__((address_space(1))) void*)(gp), \
    (__attribute__((address_space(3))) void*)(lp), 16, 0, 0)

// ---------------------------------------------------------------------------
// fused transpose + fp32->bf16: in (R x C) fp32 -> out (C x R) bf16
// ---------------------------------------------------------------------------
__global__ __launch_bounds__(256) void tcvt_kernel(const float* __restrict__ in, bf16* __restrict__ out,
                                                   int R, int C) {
    __shared__ float tile[32][33];
    int bx = blockIdx.x * 32, by = blockIdx.y * 32;
    int tx = threadIdx.x, ty = threadIdx.y;   // block (32,8)
#pragma unroll
    for (int i = 0; i < 32; i += 8)
        tile[ty + i][tx] = in[(size_t)(by + ty + i) * C + bx + tx];
    __syncthreads();
#pragma unroll
    for (int i = 0; i < 32; i += 8)
        out[(size_t)(bx + ty + i) * R + by + tx] = (bf16)tile[tx][ty + i];
}

// ---------------------------------------------------------------------------
// bf16 transpose: in (R x C) -> out (C x R)
// ---------------------------------------------------------------------------
__global__ __launch_bounds__(256) void tbf_kernel(const bf16* __restrict__ in, bf16* __restrict__ out,
                                                  int R, int C) {
    __shared__ bf16 tile[32][33];
    int bx = blockIdx.x * 32, by = blockIdx.y * 32;
    int tx = threadIdx.x, ty = threadIdx.y;   // block (32,8)
#pragma unroll
    for (int i = 0; i < 32; i += 8)
        tile[ty + i][tx] = in[(size_t)(by + ty + i) * C + bx + tx];
    __syncthreads();
#pragma unroll
    for (int i = 0; i < 32; i += 8)
        out[(size_t)(bx + ty + i) * R + by + tx] = tile[tx][ty + i];
}

// ---------------------------------------------------------------------------
// concat [bq; bk; bv] -> bqkv (3072 fp32)
// ---------------------------------------------------------------------------
__global__ __launch_bounds__(256) void bconcat_kernel(const float* __restrict__ bq, const float* __restrict__ bk,
                                                      const float* __restrict__ bv, float* __restrict__ bqkv) {
    int i = blockIdx.x * 256 + threadIdx.x;   // 3072 total
    float v = (i < 1024) ? bq[i] : (i < 2048 ? bk[i - 1024] : bv[i - 2048]);
    bqkv[i] = v;
}

// ---------------------------------------------------------------------------
// Gates (sigmoid-normalized) + selection scores (fp64 accum for deterministic
// top-k ordering) + fused fp32->bf16 conversion of x. One wave per row.
// ---------------------------------------------------------------------------
__global__ __launch_bounds__(256) void gates_scores_kernel(const float* __restrict__ x,
                                                           const float* __restrict__ Wg, const float* __restrict__ bg,
                                                           const float* __restrict__ Ws, const float* __restrict__ bs,
                                                           float* __restrict__ gates, float* __restrict__ scores,
                                                           bf16* __restrict__ xb) {
    int row = blockIdx.x * 4 + (threadIdx.x >> 6);
    int lane = threadIdx.x & 63;
    const float* xr = x + (size_t)row * 1024 + lane * 16;
    float g0 = 0.f, g1 = 0.f, g2 = 0.f;
    double sc = 0.0;
    bf16x8 xo0, xo1;
#pragma unroll
    for (int i = 0; i < 16; i++) {
        float xv = xr[i];
        if (i < 8) xo0[i] = (bf16)xv; else xo1[i - 8] = (bf16)xv;
        int k = lane * 16 + i;
        g0 += xv * Wg[k * 3 + 0];
        g1 += xv * Wg[k * 3 + 1];
        g2 += xv * Wg[k * 3 + 2];
        sc += (double)(xv * Ws[k]);
    }
    bf16* xbp = xb + (size_t)row * 1024 + lane * 16;
    *(bf16x8*)xbp = xo0;
    *(bf16x8*)(xbp + 8) = xo1;
    for (int off = 1; off < 64; off <<= 1) {
        g0 += __shfl_xor(g0, off);
        g1 += __shfl_xor(g1, off);
        g2 += __shfl_xor(g2, off);
        sc += __shfl_xor(sc, off);
    }
    if (lane == 0) {
        g0 = 1.0f / (1.0f + __expf(-(g0 + bg[0])));
        g1 = 1.0f / (1.0f + __expf(-(g1 + bg[1])));
        g2 = 1.0f / (1.0f + __expf(-(g2 + bg[2])));
        float den = g0 + g1 + g2 + 1e-6f;
        gates[(size_t)row * 3 + 0] = g0 / den;
        gates[(size_t)row * 3 + 1] = g1 / den;
        gates[(size_t)row * 3 + 2] = g2 / den;
        scores[row] = (float)(sc + (double)bs[0]);
    }
}

// ---------------------------------------------------------------------------
// Top-k stage 1: rank of each score under total order (score desc, idx asc).
// grid (16,4): 256 queries/block, all 4096 scores of the batch in LDS.
// ---------------------------------------------------------------------------
__global__ __launch_bounds__(256) void rank_kernel(const float* __restrict__ scores, int* __restrict__ ranks) {
    __shared__ float s[4096];
    int b = blockIdx.y;
    int i = blockIdx.x * 256 + threadIdx.x;
    const float* sb = scores + b * 4096;
    for (int j = threadIdx.x; j < 4096; j += 256) s[j] = sb[j];
    __syncthreads();
    float si = s[i];
    int cnt = 0;
#pragma unroll 8
    for (int j = 0; j < 4096; j++) {
        float sj = s[j];
        cnt += (sj > si) || (sj == si && j < i);
    }
    ranks[b * 4096 + i] = cnt;
}

// ---------------------------------------------------------------------------
// Top-k stage 2: compact indices with rank<512 in ascending-index order.
// One block of 1024 threads per batch (4 consecutive indices per thread).
// ---------------------------------------------------------------------------
__global__ __launch_bounds__(1024) void select_kernel(const int* __restrict__ ranks, int* __restrict__ sidx) {
    __shared__ int psum[1024];
    int b = blockIdx.x, t = threadIdx.x;
    const int* rb = ranks + b * 4096;
    int f0 = rb[4 * t + 0] < 512, f1 = rb[4 * t + 1] < 512;
    int f2 = rb[4 * t + 2] < 512, f3 = rb[4 * t + 3] < 512;
    psum[t] = f0 + f1 + f2 + f3;
    __syncthreads();
    for (int off = 1; off < 1024; off <<= 1) {
        int u = (t >= off) ? psum[t - off] : 0;
        __syncthreads();
        psum[t] += u;
        __syncthreads();
    }
    int pos = t ? psum[t - 1] : 0;
    int* ob = sidx + b * 512;
    if (f0) ob[pos++] = 4 * t + 0;
    if (f1) ob[pos++] = 4 * t + 1;
    if (f2) ob[pos++] = 4 * t + 2;
    if (f3) ob[pos++] = 4 * t + 3;
}

// ---------------------------------------------------------------------------
// Gather selected rows of Q/K/V
// ---------------------------------------------------------------------------
__global__ __launch_bounds__(256) void gather_kernel(const bf16* __restrict__ Qf, const bf16* __restrict__ Kf,
                                                     const bf16* __restrict__ Vf, const int* __restrict__ sidx,
                                                     bf16* __restrict__ sq, bf16* __restrict__ sk,
                                                     bf16* __restrict__ sv) {
    int e = blockIdx.x * 256 + threadIdx.x;
    int col = (e & 127) * 8;
    int i = (e >> 7) & 511;
    int b = e >> 16;
    int src = b * 4096 + (sidx[b * 512 + i] & 4095);
    size_t so = (size_t)src * 1024 + col;
    size_t dofs = (size_t)(b * 512 + i) * 1024 + col;
    *(float4*)(sq + dofs) = *(const float4*)(Qf + so);
    *(float4*)(sk + dofs) = *(const float4*)(Kf + so);
    *(float4*)(sv + dofs) = *(const float4*)(Vf + so);
}

// ---------------------------------------------------------------------------
// GEMM (BT only): C(M,N) = A(M,K) @ Bt(N,K)^T + bias. m97 pattern:
// 128x128 tile, 16x16x32 bf16 MFMA, 4 waves, 4x4 frags, global_load_lds(16).
// z index: NZF=false -> z=blockIdx.z split by zdiv (zh=z/zdiv, zl=z%zdiv);
//          NZF=true  -> zl=blockIdx.x/zdiv, nt=blockIdx.x%zdiv, zh=blockIdx.z
//                       (N-fused segments share A-tiles for L2 reuse).
// offsets: A += zh*sAhi + zl*sAlo; Bt += zh*sBhi + zl*sBlo; C += zh*sChi+zl*sClo
// bias[zl*biasz + gc]. F32OUT: fp32 C; ACC: C+=;
// REMAP: A-row r -> C-row (r/mpbA)*mpbC + r%mpbA.
// ---------------------------------------------------------------------------
template <bool NZF, bool F32OUT, bool ACC, bool REMAP>
__global__ __launch_bounds__(256) void gemm3(const bf16* __restrict__ A, const bf16* __restrict__ Bt,
                                             void* __restrict__ Cv, const float* __restrict__ bias, int biasz,
                                             int K, int lda, int ldb, int ldc, int zdiv,
                                             size_t sAhi, size_t sAlo, size_t sBhi, size_t sBlo,
                                             size_t sChi, size_t sClo, int mpbA, int mpbC) {
    __shared__ float4 smA[512], smB[512];  // 128x32 bf16 each
    bf16* sA = (bf16*)smA;
    bf16* sB = (bf16*)smB;
    const int t = threadIdx.x;
    const int lane = t & 63, quad = lane >> 4, l16 = lane & 15;
    const int wv = t >> 6, wm = wv >> 1, wn = wv & 1;
    const int mt = blockIdx.y;
    int nt, zh, zl;
    if constexpr (NZF) {
        zh = blockIdx.z;
        zl = blockIdx.x / zdiv;
        nt = blockIdx.x - zl * zdiv;
    } else {
        nt = blockIdx.x;
        int z = blockIdx.z;
        zh = z / zdiv;
        zl = z - zh * zdiv;
    }
    A  += (size_t)zh * sAhi + (size_t)zl * sAlo;
    Bt += (size_t)zh * sBhi + (size_t)zl * sBlo;
    const size_t cofs = (size_t)zh * sChi + (size_t)zl * sClo;

    floatx4 acc[4][4] = {};

    const bf16* Ap = A + (size_t)(mt * 128 + (t >> 2)) * lda + (t & 3) * 8;
    const bf16* Bp = Bt + (size_t)(nt * 128 + (t >> 2)) * ldb + (t & 3) * 8;
    const size_t rA = (size_t)64 * lda, rB = (size_t)64 * ldb;
    bf16* lA0 = sA + wv * 512;          // wave-uniform LDS bases
    bf16* lA1 = sA + 2048 + wv * 512;
    bf16* lB0 = sB + wv * 512;
    bf16* lB1 = sB + 2048 + wv * 512;

    for (int k0 = 0; k0 < K; k0 += 32) {
        __syncthreads();
        GLDS(Ap + k0,      lA0);
        GLDS(Ap + rA + k0, lA1);
        GLDS(Bp + k0,      lB0);
        GLDS(Bp + rB + k0, lB1);
        __syncthreads();
        bf16x8 af[4], bfr[4];
#pragma unroll
        for (int i = 0; i < 4; i++) af[i] = *(const bf16x8*)(sA + (wm * 64 + i * 16 + l16) * 32 + quad * 8);
#pragma unroll
        for (int j = 0; j < 4; j++) bfr[j] = *(const bf16x8*)(sB + (wn * 64 + j * 16 + l16) * 32 + quad * 8);
#pragma unroll
        for (int i = 0; i < 4; i++)
#pragma unroll
            for (int j = 0; j < 4; j++) acc[i][j] = MFMA16(af[i], bfr[j], acc[i][j]);
    }

#pragma unroll
    for (int i = 0; i < 4; i++) {
        int gr0 = mt * 128 + wm * 64 + i * 16 + quad * 4;
#pragma unroll
        for (int j = 0; j < 4; j++) {
            int gc = nt * 128 + wn * 64 + j * 16 + l16;
            float bvl = bias ? bias[zl * biasz + gc] : 0.0f;
#pragma unroll
            for (int r = 0; r < 4; r++) {
                int row = gr0 + r;
                size_t crow = REMAP ? ((size_t)(row / mpbA) * mpbC + (row % mpbA)) : (size_t)row;
                size_t off = cofs + crow * ldc + gc;
                float v = acc[i][j][r] + bvl;
                if constexpr (F32OUT) {
                    float* Cf = (float*)Cv;
                    if constexpr (ACC) v += Cf[off];
                    Cf[off] = v;
                } else {
                    bf16* Cb = (bf16*)Cv;
                    if constexpr (ACC) v += (float)Cb[off];
                    Cb[off] = (bf16)v;
                }
            }
        }
    }
}

// ---------------------------------------------------------------------------
// Row softmax (fp32 scores -> bf16 P, gate folded in). One block per row.
// MODE 0: comp (B*1024); MODE 1: sel (B*512); MODE 2: win (upb windows/batch).
// ---------------------------------------------------------------------------
template <int MODE>
__global__ __launch_bounds__(256) void softmax_kernel(const float* __restrict__ S, bf16* __restrict__ P,
                                                      const float* __restrict__ gates, int RL,
                                                      int upb, int wbase) {
    __shared__ float red[8];
    const int row = blockIdx.x, t = threadIdx.x;
    const float* srow = S + (size_t)row * RL;
    bf16* prow = P + (size_t)row * RL;
    const int npt = RL >> 8;
    float v[4];
    float m = -1e30f;
    for (int i = 0; i < npt; i++) { v[i] = srow[t + (i << 8)] * SCALE_F; m = fmaxf(m, v[i]); }
    for (int off = 1; off < 64; off <<= 1) m = fmaxf(m, __shfl_xor(m, off));
    const int wvv = t >> 6, lane = t & 63;
    if (lane == 0) red[wvv] = m;
    __syncthreads();
    m = fmaxf(fmaxf(red[0], red[1]), fmaxf(red[2], red[3]));
    float e[4], s = 0.f;
    for (int i = 0; i < npt; i++) { e[i] = __expf(v[i] - m); s += e[i]; }
    for (int off = 1; off < 64; off <<= 1) s += __shfl_xor(s, off);
    if (lane == 0) red[4 + wvv] = s;
    __syncthreads();
    s = red[4] + red[5] + red[6] + red[7];
    int gpos;
    if (MODE == 0)      { gpos = (row >> 10) * 4096 + (row & 1023); }
    else if (MODE == 1) { gpos = (row >> 9) * 4096 + (row & 511); }
    else                { int zz = row >> 8; gpos = (zz / upb) * 4096 + (wbase + zz % upb) * 256 + (row & 255); }
    const float fac = gates[gpos * 3 + MODE] / s;
    for (int i = 0; i < npt; i++) prow[t + (i << 8)] = (bf16)(e[i] * fac);
}

// ---------------------------------------------------------------------------
// Residual (0.5/0.5) + LayerNorm, in-place on fp32 out. One block per row.
// ---------------------------------------------------------------------------
__global__ __launch_bounds__(256) void ln_kernel(float* __restrict__ acc, const float* __restrict__ x) {
    __shared__ float red[8];
    int row = blockIdx.x, t = threadIdx.x;
    float4 a = ((const float4*)(acc + (size_t)row * 1024))[t];
    float4 xv = ((const float4*)(x + (size_t)row * 1024))[t];
    float y[4];
    y[0] = 0.5f * a.x + 0.5f * xv.x;
    y[1] = 0.5f * a.y + 0.5f * xv.y;
    y[2] = 0.5f * a.z + 0.5f * xv.z;
    y[3] = 0.5f * a.w + 0.5f * xv.w;
    float s = 0.f, s2 = 0.f;
#pragma unroll
    for (int i = 0; i < 4; i++) { s += y[i]; s2 += y[i] * y[i]; }
    for (int off = 1; off < 64; off <<= 1) { s += __shfl_xor(s, off); s2 += __shfl_xor(s2, off); }
    int wvv = t >> 6, lane = t & 63;
    if (lane == 0) { red[wvv] = s; red[4 + wvv] = s2; }
    __syncthreads();
    s = red[0] + red[1] + red[2] + red[3];
    s2 = red[4] + red[5] + red[6] + red[7];
    float mu = s * (1.0f / 1024.0f);
    float var = s2 * (1.0f / 1024.0f) - mu * mu;
    float rs = rsqrtf(var + 1e-6f);
    float4 o;
    o.x = (y[0] - mu) * rs;
    o.y = (y[1] - mu) * rs;
    o.z = (y[2] - mu) * rs;
    o.w = (y[3] - mu) * rs;
    ((float4*)(acc + (size_t)row * 1024))[t] = o;
}

// ---------------------------------------------------------------------------
extern "C" void kernel_launch(void* const* d_in, const int* in_sizes, int n_in,
                              void* d_out, int out_size, void* d_ws, size_t ws_size,
                              hipStream_t stream) {
    (void)in_sizes; (void)n_in; (void)out_size; (void)ws_size;
    const float* x  = (const float*)d_in[0];
    const float* Wq = (const float*)d_in[1];
    const float* bq = (const float*)d_in[2];
    const float* Wk = (const float*)d_in[3];
    const float* bk = (const float*)d_in[4];
    const float* Wv = (const float*)d_in[5];
    const float* bv = (const float*)d_in[6];
    const float* Wo = (const float*)d_in[7];
    const float* bo = (const float*)d_in[8];
    const float* Wg = (const float*)d_in[9];
    const float* bg = (const float*)d_in[10];
    const float* Wc = (const float*)d_in[11];
    const float* bc = (const float*)d_in[12];
    const float* Ws = (const float*)d_in[13];
    const float* bs = (const float*)d_in[14];
    float* out = (float*)d_out;

    // ---- workspace (~189 MB peak; phase-ordered region reuse) ----
    char* w = (char*)d_ws;
    const size_t MB = 1024 * 1024;
    // region A (0..32): xb [gates->compGEMM] -> Pwin [win] -> cq/ck/cv/Pcomp [comp] -> sel scratch [sel]
    bf16* xb    = (bf16*)(w + 0 * MB);    // 32
    bf16* Pwin  = (bf16*)(w + 0 * MB);    // 8
    bf16* cq    = (bf16*)(w + 0 * MB);    // 8
    bf16* ck    = (bf16*)(w + 8 * MB);    // 8
    bf16* cv    = (bf16*)(w + 16 * MB);   // 8
    bf16* Pcomp = (bf16*)(w + 24 * MB);   // 8
    float* Ssel = (float*)(w + 0 * MB);   // 4
    bf16* Psel  = (bf16*)(w + 4 * MB);    // 2
    bf16* sel_o = (bf16*)(w + 6 * MB);    // 4
    // mid regions
    bf16* qf    = (bf16*)(w + 32 * MB);   // 32 [QKV -> S_win]
    bf16* vfT   = (bf16*)(w + 32 * MB);   // 32 [after S_win]
    bf16* kf    = (bf16*)(w + 64 * MB);   // 32 [QKV -> S_win]
    bf16* win_o = (bf16*)(w + 64 * MB);   // 32 [after S_win]
    bf16* vf    = (bf16*)(w + 96 * MB);   // 32 [QKV -> vfT transpose/gather]
    bf16* comp  = (bf16*)(w + 128 * MB);  // 8  [compGEMM -> comp qkv]
    // region B (136..152): Swin [win] -> Scomp [comp] -> cvT+comp_o
    float* Swin  = (float*)(w + 136 * MB);  // 16
    float* Scomp = (float*)(w + 136 * MB);  // 16
    bf16* cvT    = (bf16*)(w + 136 * MB);   // 8
    bf16* comp_o = (bf16*)(w + 144 * MB);   // 8
    // weights (transposed bf16)
    bf16* wqkvT = (bf16*)(w + 152 * MB);  // 6 (wq|wk|wv, 1024-row segments)
    bf16* wcT   = (bf16*)(w + 158 * MB);  // 8
    bf16* woT0  = (bf16*)(w + 166 * MB);  // 2
    bf16* woT1  = (bf16*)(w + 168 * MB);  // 2
    bf16* woT2  = (bf16*)(w + 170 * MB);  // 2
    // sel gather buffers (parked high; live gather -> sel branch)
    bf16* sq    = (bf16*)(w + 172 * MB);  // 4
    bf16* sk    = (bf16*)(w + 176 * MB);  // 4
    bf16* sv    = (bf16*)(w + 180 * MB);  // 4
    bf16* svT   = (bf16*)(w + 184 * MB);  // 4
    // smalls
    float* bqkv    = (float*)(w + 188 * MB);
    float* gatesF  = bqkv + 3072;
    float* scoresF = gatesF + 49152;
    int*   ranks   = (int*)(scoresF + 16384);
    int*   sidx    = ranks + 16384;

    dim3 tb(32, 8);

    // ---- prep: gates+scores+x->bf16 (fused), weight transposes, bias concat, topk ----
    gates_scores_kernel<<<4096, 256, 0, stream>>>(x, Wg, bg, Ws, bs, gatesF, scoresF, xb);
    tcvt_kernel<<<dim3(32, 32), tb, 0, stream>>>(Wq, wqkvT, 1024, 1024);
    tcvt_kernel<<<dim3(32, 32), tb, 0, stream>>>(Wk, wqkvT + (size_t)1048576, 1024, 1024);
    tcvt_kernel<<<dim3(32, 32), tb, 0, stream>>>(Wv, wqkvT + (size_t)2097152, 1024, 1024);
    tcvt_kernel<<<dim3(32, 128), tb, 0, stream>>>(Wc, wcT, 4096, 1024);
    tcvt_kernel<<<dim3(32, 32), tb, 0, stream>>>(Wo, woT0, 1024, 1024);
    tcvt_kernel<<<dim3(32, 32), tb, 0, stream>>>(Wo + (size_t)1048576, woT1, 1024, 1024);
    tcvt_kernel<<<dim3(32, 32), tb, 0, stream>>>(Wo + (size_t)2097152, woT2, 1024, 1024);
    bconcat_kernel<<<12, 256, 0, stream>>>(bq, bk, bv, bqkv);
    rank_kernel<<<dim3(16, 4), 256, 0, stream>>>(scoresF, ranks);
    select_kernel<<<4, 1024, 0, stream>>>(ranks, sidx);

    // ---- fused Q/K/V: one dispatch, N-fused z (A-tile reused across Q,K,V) ----
    gemm3<true,false,false,false><<<dim3(24, 128, 1), 256, 0, stream>>>(
        xb, wqkvT, qf, bqkv, 1024, 1024, 1024, 1024, 1024, 8,
        0, 0, 0, (size_t)1048576, 0, (size_t)16777216, 1, 1);
    // ---- compressed tokens: xb viewed (4096,4096) @ wcT^T (last xb reader) ----
    gemm3<false,false,false,false><<<dim3(8, 32, 1), 256, 0, stream>>>(
        xb, wcT, comp, bc, 0, 4096, 4096, 4096, 1024, 1, 0, 0, 0, 0, 0, 0, 1, 1);

    gather_kernel<<<1024, 256, 0, stream>>>(qf, kf, vf, sidx, sq, sk, sv);

    // ---- WIN branch first (win proj covers all rows: ACC=false + bias) ----
    gemm3<false,true,false,false><<<dim3(2, 2, 64), 256, 0, stream>>>(
        qf, kf, Swin, nullptr, 0, 1024, 1024, 1024, 256, 16,
        (size_t)4194304, (size_t)131072, (size_t)4194304, (size_t)131072, (size_t)1048576, (size_t)65536, 1, 1);
    softmax_kernel<2><<<16384, 256, 0, stream>>>(Swin, Pwin, gatesF, 256, 16, 0);
    tbf_kernel<<<dim3(32, 512), tb, 0, stream>>>(vf, vfT, 16384, 1024);   // qf dead after S_win
    gemm3<false,false,false,false><<<dim3(8, 2, 64), 256, 0, stream>>>(
        Pwin, vfT, win_o, nullptr, 0, 256, 256, 16384, 1024, 16,
        (size_t)1048576, (size_t)65536, (size_t)4096, (size_t)128, (size_t)4194304, (size_t)262144, 1, 1);
    gemm3<false,true,false,false><<<dim3(8, 128, 1), 256, 0, stream>>>(
        win_o, woT2, out, bo, 0, 1024, 1024, 1024, 1024, 1, 0, 0, 0, 0, 0, 0, 1, 1);

    // ---- COMP branch (fused comp QKV, N-fused z) ----
    gemm3<true,false,false,false><<<dim3(24, 32, 1), 256, 0, stream>>>(
        comp, wqkvT, cq, bqkv, 1024, 1024, 1024, 1024, 1024, 8,
        0, 0, 0, (size_t)1048576, 0, (size_t)4194304, 1, 1);
    gemm3<false,true,false,false><<<dim3(8, 8, 4), 256, 0, stream>>>(
        cq, ck, Scomp, nullptr, 0, 1024, 1024, 1024, 1024, 1,
        (size_t)1048576, 0, (size_t)1048576, 0, (size_t)1048576, 0, 1, 1);
    softmax_kernel<0><<<4096, 256, 0, stream>>>(Scomp, Pcomp, gatesF, 1024, 0, 0);
    tbf_kernel<<<dim3(32, 128), tb, 0, stream>>>(cv, cvT, 4096, 1024);    // Scomp dead
    gemm3<false,false,false,false><<<dim3(8, 8, 4), 256, 0, stream>>>(
        Pcomp, cvT, comp_o, nullptr, 0, 1024, 1024, 4096, 1024, 1,
        (size_t)1048576, 0, (size_t)1024, 0, (size_t)1048576, 0, 1, 1);
    gemm3<false,true,true,true><<<dim3(8, 32, 1), 256, 0, stream>>>(
        comp_o, woT0, out, nullptr, 0, 1024, 1024, 1024, 1024, 1, 0, 0, 0, 0, 0, 0, 1024, 4096);

    // ---- SEL branch ----
    gemm3<false,true,false,false><<<dim3(4, 4, 4), 256, 0, stream>>>(
        sq, sk, Ssel, nullptr, 0, 1024, 1024, 1024, 512, 1,
        (size_t)524288, 0, (size_t)524288, 0, (size_t)262144, 0, 1, 1);
    softmax_kernel<1><<<2048, 256, 0, stream>>>(Ssel, Psel, gatesF, 512, 0, 0);
    tbf_kernel<<<dim3(32, 64), tb, 0, stream>>>(sv, svT, 2048, 1024);
    gemm3<false,false,false,false><<<dim3(8, 4, 4), 256, 0, stream>>>(
        Psel, svT, sel_o, nullptr, 0, 512, 512, 2048, 1024, 1,
        (size_t)262144, 0, (size_t)512, 0, (size_t)524288, 0, 1, 1);
    gemm3<false,true,true,true><<<dim3(8, 16, 1), 256, 0, stream>>>(
        sel_o, woT1, out, nullptr, 0, 1024, 1024, 1024, 1024, 1, 0, 0, 0, 0, 0, 0, 512, 4096);

    // ---- residual + LN in place on fp32 d_out ----
    ln_kernel<<<16384, 256, 0, stream>>>(out, x);
}